// Round 18
// baseline (204.461 us; speedup 1.0000x reference)
//
#include <hip/hip_runtime.h>
#include <hip/hip_bf16.h>
#include <math.h>

#define NB 2
#define SEQ 1024
#define HDIM 2048
#define NHEADS 16
#define HDHEAD 128
#define PASTN 1024
#define STOT 2048
#define MROWS 2048   // NB*SEQ

typedef __attribute__((ext_vector_type(4))) float f32x4;
typedef __attribute__((ext_vector_type(8))) __bf16 bf16x8;
typedef __attribute__((ext_vector_type(8))) unsigned short us8;
typedef __attribute__((ext_vector_type(4))) unsigned short us4;

__device__ __forceinline__ unsigned short f2bf(float f) {
    union { float f; unsigned int u; } v; v.f = f;
    unsigned int u = v.u;
    u += 0x7FFFu + ((u >> 16) & 1u);
    return (unsigned short)(u >> 16);
}
__device__ __forceinline__ bf16x8 as_bf(us8 u) { return __builtin_bit_cast(bf16x8, u); }

// async global->LDS, 16B per lane; LDS dest is wave-uniform base + lane*16
__device__ __forceinline__ void gl16(const unsigned short* g, unsigned short* l) {
    __builtin_amdgcn_global_load_lds(
        (const __attribute__((address_space(1))) void*)g,
        (__attribute__((address_space(3))) void*)l, 16, 0, 0);
}

// ---------------- ws layout (bytes) ----------------
#define OFF_CS  ((size_t)0)                              // float2[SEQ*64] = 512 KB
#define OFF_HSB (OFF_CS  + (size_t)SEQ*64*8)
#define OFF_WT  (OFF_HSB + (size_t)MROWS*HDIM*2)
#define OFF_QBF (OFF_WT  + (size_t)4*HDIM*HDIM*2)
#define OFF_KC  (OFF_QBF + (size_t)NB*NHEADS*SEQ*HDHEAD*2)
#define OFF_VT  (OFF_KC  + (size_t)NB*NHEADS*STOT*HDHEAD*2)
#define OFF_ATT (OFF_VT  + (size_t)NB*NHEADS*HDHEAD*STOT*2)
// NOTE: the ATT region (16.8 MB) doubles as C_k scratch (2048x2048 fp32) for
// k_gemm_qkv -> k_post; attn overwrites it afterwards (stream-ordered, safe).
// C_q scratch (2048x2048 fp32) lives in d_out's out0 region (written last).

// K cache tiled layout: Kc2[(bh*32+kt)*8192 + pr*128 + (d ^ ((p&7)<<3))], pr=p&63
// V cache tiled layout: Vt2[(bh*32+kt)*8192 + d*64 + ((p&63) ^ ((d&7)<<3))]

// ---------------- prep: hidden cvt + rope table | W transpose ----------------
__global__ void k_prep(const float* __restrict__ in, unsigned short* __restrict__ hsb,
                       float2* __restrict__ csT,
                       const float* __restrict__ Wq, const float* __restrict__ Wk,
                       const float* __restrict__ Wv, const float* __restrict__ Wo,
                       unsigned short* __restrict__ WT) {
    __shared__ unsigned short tsh[64][65];
    const int bid = blockIdx.x, tid = threadIdx.x;
    if (bid < 4096) {
        const int i = (bid * 256 + tid) * 4;           // over 4M elems
        f32x4 v = *(const f32x4*)(in + i);
        us4 o;
        o.x = f2bf(v.x); o.y = f2bf(v.y); o.z = f2bf(v.z); o.w = f2bf(v.w);
        *(us4*)(hsb + i) = o;
        if (bid < 256) {                                // rope cos/sin table
            const int idx = bid * 256 + tid;
            const int s = idx >> 6, fi = idx & 63;
            float inv = 1.0f / powf(10000.0f, (float)fi / 64.0f);
            float a = (float)s * inv;
            csT[idx] = make_float2(cosf(a), sinf(a));
        }
    } else {
        // W [K][N] fp32 -> WT [N][K] bf16 ; 64x64 tile, full-line writes
        const int idx = bid - 4096;
        const int z = idx >> 10;
        const int rem = idx & 1023;
        const int n0 = (rem & 31) * 64, k0 = (rem >> 5) * 64;
        const float* W = (z == 0) ? Wq : (z == 1) ? Wk : (z == 2) ? Wv : Wo;
        unsigned short* out = WT + (size_t)z * HDIM * HDIM;
        const int tx = tid & 63, ty = tid >> 6;         // (64,4)
        #pragma unroll
        for (int j = 0; j < 16; ++j) {
            const int kk = ty + j * 4;
            tsh[tx][kk] = f2bf(W[(size_t)(k0 + kk) * HDIM + n0 + tx]);   // tsh[n][k]
        }
        __syncthreads();
        #pragma unroll
        for (int j = 0; j < 16; ++j) {
            const int nn = ty + j * 4;
            out[(size_t)(n0 + nn) * HDIM + k0 + tx] = tsh[nn][tx];       // 128B row runs
        }
    }
}

// ---------------- QKV GEMM (blocks 0-191) + pastk (192-223) + pastv (224-255) ----
__global__ __launch_bounds__(512, 2) void k_gemm_qkv(
    const unsigned short* __restrict__ hsb, const unsigned short* __restrict__ WT,
    const float* __restrict__ bv,
    float* __restrict__ Cq, float* __restrict__ Ck, float* __restrict__ outV,
    const float* __restrict__ pk, const float* __restrict__ pv,
    float* __restrict__ outK, unsigned short* __restrict__ Kc2,
    unsigned short* __restrict__ Vt2) {
    __shared__ __align__(16) unsigned short As[2][256 * 64];
    __shared__ __align__(16) unsigned short Bs[2][256 * 64];

    const int bid = blockIdx.x;
    const int t = threadIdx.x;

    if (bid >= 192) {
        if (bid < 224) {
            // ---- pastk: fp32 copy + bf16 tiled/swizzled (grid-stride, 512 thr) ----
            const int blk = bid - 192;   // 0..31
            for (int it = 0; it < 64; ++it) {
                const size_t e = ((size_t)(blk * 64 + it) * 512 + t) * 4;
                const size_t bh = e >> 17;
                const int p = (int)((e >> 7) & 1023);
                const int d0 = (int)(e & 127);
                f32x4 v = *(const f32x4*)(pk + e);
                *(f32x4*)(outK + e + (bh << 17)) = v;
                us4 u;
                u.x = f2bf(v.x); u.y = f2bf(v.y); u.z = f2bf(v.z); u.w = f2bf(v.w);
                *(us4*)(Kc2 + ((bh * 32 + (p >> 6)) << 13) + (size_t)(p & 63) * 128 +
                        (d0 ^ ((p & 7) << 3))) = u;
            }
        } else {
            // ---- pastv: fp32 copy + tiled/swizzled bf16 (32 tiles/block, 512 thr) ----
            const int blk = bid - 224;   // 0..31
            unsigned short (*tsh)[65] = (unsigned short (*)[65])As;   // reuse LDS
            const int tx = t & 63, ty = t >> 6;     // (64,8)
            for (int tt = 0; tt < 32; ++tt) {
                const int tile = blk * 32 + tt;
                const int bh = tile >> 5;
                const int rem = tile & 31;
                const int p0 = (rem & 15) * 64, d0 = (rem >> 4) * 64;
                const float* src = pv + ((size_t)bh * PASTN + p0) * HDHEAD + d0;
                float* dst = outV + ((size_t)bh * STOT + p0) * HDHEAD + d0;
                #pragma unroll
                for (int j = 0; j < 8; ++j) {
                    const int pp = ty + j * 8;
                    float v = src[(size_t)pp * HDHEAD + tx];
                    dst[(size_t)pp * HDHEAD + tx] = v;
                    tsh[tx][pp] = f2bf(v);           // tsh[d_off][p_off]
                }
                __syncthreads();
                unsigned short* vt = Vt2 + (((size_t)bh * 32 + (p0 >> 6)) << 13);
                #pragma unroll
                for (int j = 0; j < 8; ++j) {
                    const int dd = ty + j * 8;
                    const int d = d0 + dd;
                    vt[(size_t)d * 64 + (tx ^ ((d & 7) << 3))] = tsh[dd][tx];
                }
                __syncthreads();
            }
        }
        return;
    }

    const int swz = (bid & 7) * 24 + (bid >> 3);
    const int mb = swz & 7;
    const int nbz = swz >> 3;
    const int z = nbz >> 3;            // 0:q 1:k 2:v
    const int nb8 = nbz & 7;
    const int m0 = mb * 256;
    const int n0 = nb8 * 256;
    const unsigned short* Wz = WT + (size_t)z * HDIM * HDIM;

    const int lane = t & 63, wid = t >> 6;
    const int wr = wid >> 1, wc = wid & 1;
    const int c = lane & 15, g = lane >> 4;

    const int lrow8 = lane >> 3;
    const int lslot = (lane & 7) ^ lrow8;
    const unsigned short* aB = hsb + (size_t)(m0 + lrow8) * HDIM + lslot * 8;
    const unsigned short* bB = Wz + (size_t)(n0 + lrow8) * HDIM + lslot * 8;

    auto stage = [&](int kt, int pb) {
        const int k0s = kt * 64;
        #pragma unroll
        for (int j = 0; j < 4; ++j) {
            const int ch = wid * 4 + j;
            gl16(aB + (size_t)(ch * 8) * HDIM + k0s, &As[pb][ch * 512]);
            gl16(bB + (size_t)(ch * 8) * HDIM + k0s, &Bs[pb][ch * 512]);
        }
    };

    f32x4 acc[4][8] = {};
    const int NT = HDIM / 64;  // 32

    stage(0, 0);
    stage(1, 1);

#define MF(A_, B_, C_) __builtin_amdgcn_mfma_f32_16x16x32_bf16(A_, B_, C_, 0, 0, 0)
#define RDA(D0, D1, MI) { const int ar_ = wr * 64 + (MI) * 16 + c; const int sa_ = ar_ & 7; \
    D0 = as_bf(*(const us8*)&As[p][ar_ * 64 + ((g ^ sa_) << 3)]); \
    D1 = as_bf(*(const us8*)&As[p][ar_ * 64 + (((4 + g) ^ sa_) << 3)]); }
#define RDB0(NI) { const int br_ = wc * 128 + (NI) * 16 + c; const int sb_ = br_ & 7; \
    b0[NI] = as_bf(*(const us8*)&Bs[p][br_ * 64 + ((g ^ sb_) << 3)]); }
#define RDB1(NI) { const int br_ = wc * 128 + (NI) * 16 + c; const int sb_ = br_ & 7; \
    b1[NI] = as_bf(*(const us8*)&Bs[p][br_ * 64 + (((4 + g) ^ sb_) << 3)]); }

    for (int kt = 0; kt < NT; ++kt) {
        const int p = kt & 1;
        if (kt + 1 < NT) {
            asm volatile("s_waitcnt vmcnt(8)" ::: "memory");
        } else {
            asm volatile("s_waitcnt vmcnt(0)" ::: "memory");
        }
        __builtin_amdgcn_s_barrier();

        bf16x8 b0[8], b1[8];
        bf16x8 a0c, a1c, a0n, a1n;
        RDA(a0c, a1c, 0)
        RDB0(0) RDB0(1) RDB0(2) RDB0(3)
        __builtin_amdgcn_s_setprio(1);
        // ---- mi=0: interleave remaining B reads 1-per-MFMA ----
        RDB0(4) acc[0][0] = MF(a0c, b0[0], acc[0][0]);
        RDB0(5) acc[0][1] = MF(a0c, b0[1], acc[0][1]);
        RDB0(6) acc[0][2] = MF(a0c, b0[2], acc[0][2]);
        RDB0(7) acc[0][3] = MF(a0c, b0[3], acc[0][3]);
        RDB1(0) acc[0][4] = MF(a0c, b0[4], acc[0][4]);
        RDB1(1) acc[0][5] = MF(a0c, b0[5], acc[0][5]);
        RDB1(2) acc[0][6] = MF(a0c, b0[6], acc[0][6]);
        RDB1(3) acc[0][7] = MF(a0c, b0[7], acc[0][7]);
        RDB1(4) acc[0][0] = MF(a1c, b1[0], acc[0][0]);
        RDB1(5) acc[0][1] = MF(a1c, b1[1], acc[0][1]);
        RDB1(6) acc[0][2] = MF(a1c, b1[2], acc[0][2]);
        RDB1(7) acc[0][3] = MF(a1c, b1[3], acc[0][3]);
        RDA(a0n, a1n, 1)
        acc[0][4] = MF(a1c, b1[4], acc[0][4]);
        acc[0][5] = MF(a1c, b1[5], acc[0][5]);
        acc[0][6] = MF(a1c, b1[6], acc[0][6]);
        acc[0][7] = MF(a1c, b1[7], acc[0][7]);
        // ---- mi=1 (uses a0n/a1n), prefetch A(2) mid-cluster ----
        acc[1][0] = MF(a0n, b0[0], acc[1][0]);
        acc[1][1] = MF(a0n, b0[1], acc[1][1]);
        acc[1][2] = MF(a0n, b0[2], acc[1][2]);
        acc[1][3] = MF(a0n, b0[3], acc[1][3]);
        acc[1][4] = MF(a0n, b0[4], acc[1][4]);
        acc[1][5] = MF(a0n, b0[5], acc[1][5]);
        acc[1][6] = MF(a0n, b0[6], acc[1][6]);
        acc[1][7] = MF(a0n, b0[7], acc[1][7]);
        RDA(a0c, a1c, 2)
        acc[1][0] = MF(a1n, b1[0], acc[1][0]);
        acc[1][1] = MF(a1n, b1[1], acc[1][1]);
        acc[1][2] = MF(a1n, b1[2], acc[1][2]);
        acc[1][3] = MF(a1n, b1[3], acc[1][3]);
        acc[1][4] = MF(a1n, b1[4], acc[1][4]);
        acc[1][5] = MF(a1n, b1[5], acc[1][5]);
        acc[1][6] = MF(a1n, b1[6], acc[1][6]);
        acc[1][7] = MF(a1n, b1[7], acc[1][7]);
        // ---- mi=2 (uses a0c/a1c), prefetch A(3) mid-cluster ----
        acc[2][0] = MF(a0c, b0[0], acc[2][0]);
        acc[2][1] = MF(a0c, b0[1], acc[2][1]);
        acc[2][2] = MF(a0c, b0[2], acc[2][2]);
        acc[2][3] = MF(a0c, b0[3], acc[2][3]);
        acc[2][4] = MF(a0c, b0[4], acc[2][4]);
        acc[2][5] = MF(a0c, b0[5], acc[2][5]);
        acc[2][6] = MF(a0c, b0[6], acc[2][6]);
        acc[2][7] = MF(a0c, b0[7], acc[2][7]);
        RDA(a0n, a1n, 3)
        acc[2][0] = MF(a1c, b1[0], acc[2][0]);
        acc[2][1] = MF(a1c, b1[1], acc[2][1]);
        acc[2][2] = MF(a1c, b1[2], acc[2][2]);
        acc[2][3] = MF(a1c, b1[3], acc[2][3]);
        acc[2][4] = MF(a1c, b1[4], acc[2][4]);
        acc[2][5] = MF(a1c, b1[5], acc[2][5]);
        acc[2][6] = MF(a1c, b1[6], acc[2][6]);
        acc[2][7] = MF(a1c, b1[7], acc[2][7]);
        // ---- mi=3 (uses a0n/a1n) ----
        acc[3][0] = MF(a0n, b0[0], acc[3][0]);
        acc[3][1] = MF(a0n, b0[1], acc[3][1]);
        acc[3][2] = MF(a0n, b0[2], acc[3][2]);
        acc[3][3] = MF(a0n, b0[3], acc[3][3]);
        acc[3][4] = MF(a0n, b0[4], acc[3][4]);
        acc[3][5] = MF(a0n, b0[5], acc[3][5]);
        acc[3][6] = MF(a0n, b0[6], acc[3][6]);
        acc[3][7] = MF(a0n, b0[7], acc[3][7]);
        acc[3][0] = MF(a1n, b1[0], acc[3][0]);
        acc[3][1] = MF(a1n, b1[1], acc[3][1]);
        acc[3][2] = MF(a1n, b1[2], acc[3][2]);
        acc[3][3] = MF(a1n, b1[3], acc[3][3]);
        acc[3][4] = MF(a1n, b1[4], acc[3][4]);
        acc[3][5] = MF(a1n, b1[5], acc[3][5]);
        acc[3][6] = MF(a1n, b1[6], acc[3][6]);
        acc[3][7] = MF(a1n, b1[7], acc[3][7]);
        __builtin_amdgcn_s_setprio(0);
        __builtin_amdgcn_s_barrier();       // all reads of buf p done
        if (kt + 2 < NT) stage(kt + 2, p);
    }
#undef MF
#undef RDA
#undef RDB0
#undef RDB1

    // ---- minimal epilogue ----
    if (z < 2) {
        float* Cz = (z == 0) ? Cq : Ck;
        #pragma unroll
        for (int mi = 0; mi < 4; ++mi) {
            #pragma unroll
            for (int r = 0; r < 4; ++r) {
                const size_t row = (size_t)(m0 + wr * 64 + mi * 16 + g * 4 + r);
                #pragma unroll
                for (int ni = 0; ni < 8; ++ni)
                    Cz[row * HDIM + n0 + wc * 128 + ni * 16 + c] = acc[mi][ni][r];
            }
        }
    } else {
        const int h = nb8 * 2 + wc;
        const int b = m0 >> 10;
        const size_t bh2 = (size_t)(b * NHEADS + h);
        float bias8[8];
        #pragma unroll
        for (int ni = 0; ni < 8; ++ni) bias8[ni] = bv[n0 + wc * 128 + ni * 16 + c];
        #pragma unroll
        for (int mi = 0; mi < 4; ++mi) {
            #pragma unroll
            for (int r = 0; r < 4; ++r) {
                const int row = m0 + wr * 64 + mi * 16 + g * 4 + r;
                const int s = row & 1023;
                const int p = PASTN + s;
                #pragma unroll
                for (int ni = 0; ni < 8; ++ni)
                    outV[(bh2 * STOT + p) * HDHEAD + ni * 16 + c] = acc[mi][ni][r] + bias8[ni];
            }
        }
    }
}

// ---------------- post: bias + RoPE + cache-pack (memory-bound) ----------------
__global__ __launch_bounds__(256) void k_post(
    const float* __restrict__ Cq, const float* __restrict__ Ck,
    const float* __restrict__ outV,
    const float* __restrict__ bq, const float* __restrict__ bk,
    const float2* __restrict__ csT,
    unsigned short* __restrict__ qbf, unsigned short* __restrict__ Kc2,
    unsigned short* __restrict__ Vt2, float* __restrict__ outK) {
    __shared__ unsigned short tv[128][80];
    const int stile = blockIdx.x;       // 0..15
    const int bh = blockIdx.y;          // 0..31
    const int b = bh >> 4, h = bh & 15;
    const int tid = threadIdx.x;
    const int dq = (tid & 15) * 4;      // d0 in [0,64)
    const int sl0 = tid >> 4;           // 0..15
    const int s0 = stile * 64;
    const int ktv = 16 + stile;
    const float qscale = 0.08838834764831845f * 1.44269504088896f;  // 1/sqrt(128)*log2e
    unsigned short* kc = Kc2 + (((size_t)bh * 32 + ktv) << 13);
    unsigned short* vt = Vt2 + (((size_t)bh * 32 + ktv) << 13);

    float bql[4], bqh[4], bkl[4], bkh[4];
    #pragma unroll
    for (int i = 0; i < 4; ++i) {
        bql[i] = bq[h * 128 + dq + i];      bqh[i] = bq[h * 128 + 64 + dq + i];
        bkl[i] = bk[h * 128 + dq + i];      bkh[i] = bk[h * 128 + 64 + dq + i];
    }

    #pragma unroll
    for (int ps = 0; ps < 4; ++ps) {
        const int sl = sl0 + ps * 16;
        const int s = s0 + sl;
        const size_t row = (size_t)b * 1024 + s;
        const int p = PASTN + s;
        float2 cs4[4];
        #pragma unroll
        for (int i = 0; i < 4; ++i) cs4[i] = csT[s * 64 + dq + i];
        const int swzp = (sl & 7) << 3;     // p&7 == sl&7 (s0 is 64-aligned)
        // ---- Q ----
        {
            const f32x4 a = *(const f32x4*)&Cq[row * HDIM + h * 128 + dq];
            const f32x4 bb = *(const f32x4*)&Cq[row * HDIM + h * 128 + dq + 64];
            us4 lo, hi;
            #pragma unroll
            for (int i = 0; i < 4; ++i) {
                const float va = a[i] + bql[i];
                const float vb = bb[i] + bqh[i];
                lo[i] = f2bf((va * cs4[i].x - vb * cs4[i].y) * qscale);
                hi[i] = f2bf((vb * cs4[i].x + va * cs4[i].y) * qscale);
            }
            unsigned short* qrow = qbf + ((size_t)bh * SEQ + s) * HDHEAD;
            *(us4*)&qrow[dq] = lo;
            *(us4*)&qrow[dq + 64] = hi;
        }
        // ---- K ----
        {
            const f32x4 a = *(const f32x4*)&Ck[row * HDIM + h * 128 + dq];
            const f32x4 bb = *(const f32x4*)&Ck[row * HDIM + h * 128 + dq + 64];
            f32x4 rl, rh;
            us4 lo, hi;
            #pragma unroll
            for (int i = 0; i < 4; ++i) {
                const float va = a[i] + bkl[i];
                const float vb = bb[i] + bkh[i];
                rl[i] = va * cs4[i].x - vb * cs4[i].y;
                rh[i] = vb * cs4[i].x + va * cs4[i].y;
                lo[i] = f2bf(rl[i]);
                hi[i] = f2bf(rh[i]);
            }
            float* krow = outK + ((size_t)bh * STOT + p) * HDHEAD;
            *(f32x4*)&krow[dq] = rl;
            *(f32x4*)&krow[dq + 64] = rh;
            *(us4*)&kc[(size_t)sl * 128 + (dq ^ swzp)] = lo;
            *(us4*)&kc[(size_t)sl * 128 + ((dq + 64) ^ swzp)] = hi;
        }
        // ---- V: stage to LDS for transpose ----
        {
            const f32x4 va = *(const f32x4*)&outV[((size_t)bh * STOT + p) * HDHEAD + dq];
            const f32x4 vb = *(const f32x4*)&outV[((size_t)bh * STOT + p) * HDHEAD + dq + 64];
            #pragma unroll
            for (int i = 0; i < 4; ++i) {
                tv[dq + i][sl] = f2bf(va[i]);
                tv[dq + 64 + i][sl] = f2bf(vb[i]);
            }
        }
    }
    __syncthreads();
    // ---- Vt2 write: full-row us4 runs ----
    const int d = tid >> 1;
    const int ph = (tid & 1) * 32;
    const int swzd = (d & 7) << 3;
    #pragma unroll
    for (int i = 0; i < 8; ++i) {
        const int pp = ph + i * 4;
        us4 u;
        u.x = tv[d][pp]; u.y = tv[d][pp + 1]; u.z = tv[d][pp + 2]; u.w = tv[d][pp + 3];
        *(us4*)&vt[(size_t)d * 64 + (pp ^ swzd)] = u;
    }
}

// ---------------- flash attention: 4 waves, q-tile 64, 512 blocks ----------------
// XCD-affine + causal balance (R17) + T5 setprio around MFMA clusters.
__global__ __launch_bounds__(256) void k_attn(
    const unsigned short* __restrict__ qbf, const unsigned short* __restrict__ Kc2,
    const unsigned short* __restrict__ Vt2, unsigned short* __restrict__ attn) {
    __shared__ __align__(16) unsigned short Ks[2][64 * 128];  // 32 KB
    __shared__ __align__(16) unsigned short Vs[128 * 64];     // 16 KB
    __shared__ __align__(16) unsigned short P[4][16][72];     // 9 KB
    const int bid = blockIdx.x;
    const int bh = bid & 31;
    const int qt = (bid < 256) ? (bid >> 5) : (15 - ((bid >> 5) & 7));
    const int b = bh >> 4, h = bh & 15;
    const int t = threadIdx.x, lane = t & 63, w = t >> 6;     // 4 waves
    const int c = lane & 15, g = lane >> 4;
    const int q0 = qt * 64 + w * 16;
    const unsigned short* Qb = qbf + ((size_t)bh * SEQ + q0) * HDHEAD;
    const unsigned short* Kbase = Kc2 + ((size_t)bh << 18);
    const unsigned short* Vbase = Vt2 + ((size_t)bh << 18);

    bf16x8 qf[4];
    #pragma unroll
    for (int kf = 0; kf < 4; ++kf)
        qf[kf] = as_bf(*(const us8*)(Qb + (size_t)c * HDHEAD + kf * 32 + g * 8));

    // prologue: stage K tile 0 (16 chunks over 4 waves)
    #pragma unroll
    for (int j = 0; j < 4; ++j) {
        const int ch = w * 4 + j;
        gl16(Kbase + ch * 512 + lane * 8, &Ks[0][ch * 512]);
    }

    f32x4 o[8] = {};
    float mrow[4] = {-1e30f, -1e30f, -1e30f, -1e30f};
    float lrow[4] = {0.f, 0.f, 0.f, 0.f};
    const int nkt = 17 + qt;
    int cur = 0;
    for (int kt = 0; kt < nkt; ++kt) {
        asm volatile("s_waitcnt vmcnt(0)" ::: "memory");
        __builtin_amdgcn_s_barrier();
        const unsigned short* Vg = Vbase + ((size_t)kt << 13);
        #pragma unroll
        for (int j = 0; j < 4; ++j) {
            const int ch = w * 4 + j;
            gl16(Vg + ch * 512 + lane * 8, &Vs[ch * 512]);
        }
        if (kt + 1 < nkt) {
            const unsigned short* Kg = Kbase + ((size_t)(kt + 1) << 13);
            #pragma unroll
            for (int j = 0; j < 4; ++j) {
                const int ch = w * 4 + j;
                gl16(Kg + ch * 512 + lane * 8, &Ks[cur ^ 1][ch * 512]);
            }
        }
        // QK^T from Ks[cur]
        f32x4 sa[4] = {};
        __builtin_amdgcn_s_setprio(1);
        #pragma unroll
        for (int nf = 0; nf < 4; ++nf) {
            const int row = nf * 16 + c;
            const int swzr = (row & 7) << 3;
            #pragma unroll
            for (int kf = 0; kf < 4; ++kf) {
                bf16x8 kf8 = as_bf(*(const us8*)&Ks[cur][row * 128 + ((kf * 32 + g * 8) ^ swzr)]);
                sa[nf] = __builtin_amdgcn_mfma_f32_16x16x32_bf16(qf[kf], kf8, sa[nf], 0, 0, 0);
            }
        }
        __builtin_amdgcn_s_setprio(0);
        const int k0 = kt * 64;
        if (k0 + 63 > PASTN + q0) {
            #pragma unroll
            for (int nf = 0; nf < 4; ++nf) {
                const int j = k0 + nf * 16 + c;
                #pragma unroll
                for (int r = 0; r < 4; ++r)
                    if (j > PASTN + q0 + g * 4 + r) sa[nf][r] = -1e30f;
            }
        }
        // defer-max online softmax (log2 domain)
        float pmax[4];
        #pragma unroll
        for (int r = 0; r < 4; ++r)
            pmax[r] = fmaxf(fmaxf(sa[0][r], sa[1][r]), fmaxf(sa[2][r], sa[3][r]));
        bool need = false;
        #pragma unroll
        for (int r = 0; r < 4; ++r) need = need || (pmax[r] > mrow[r] + 12.0f);
        if (__any(need)) {
            #pragma unroll
            for (int r = 0; r < 4; ++r) {
                float mx = pmax[r];
                mx = fmaxf(mx, __shfl_xor(mx, 1));
                mx = fmaxf(mx, __shfl_xor(mx, 2));
                mx = fmaxf(mx, __shfl_xor(mx, 4));
                mx = fmaxf(mx, __shfl_xor(mx, 8));
                const float mnew = fmaxf(mrow[r], mx);
                const float alpha = exp2f(mrow[r] - mnew);
                mrow[r] = mnew;
                lrow[r] *= alpha;
                #pragma unroll
                for (int nd = 0; nd < 8; ++nd) o[nd][r] *= alpha;
            }
        }
        #pragma unroll
        for (int r = 0; r < 4; ++r) {
            const float p0 = exp2f(sa[0][r] - mrow[r]);
            const float p1 = exp2f(sa[1][r] - mrow[r]);
            const float p2 = exp2f(sa[2][r] - mrow[r]);
            const float p3 = exp2f(sa[3][r] - mrow[r]);
            lrow[r] += (p0 + p1) + (p2 + p3);
            P[w][g * 4 + r][0 * 16 + c] = f2bf(p0);
            P[w][g * 4 + r][1 * 16 + c] = f2bf(p1);
            P[w][g * 4 + r][2 * 16 + c] = f2bf(p2);
            P[w][g * 4 + r][3 * 16 + c] = f2bf(p3);
        }
        if (kt + 1 < nkt) {
            asm volatile("s_waitcnt vmcnt(4)" ::: "memory");
        } else {
            asm volatile("s_waitcnt vmcnt(0)" ::: "memory");
        }
        __builtin_amdgcn_s_barrier();
        __builtin_amdgcn_s_setprio(1);
        #pragma unroll
        for (int kf2 = 0; kf2 < 2; ++kf2) {
            const bf16x8 pa = as_bf(*(const us8*)&P[w][c][kf2 * 32 + g * 8]);
            #pragma unroll
            for (int nd = 0; nd < 8; ++nd) {
                const int d = nd * 16 + c;
                const bf16x8 vf = as_bf(*(const us8*)&Vs[d * 64 + ((kf2 * 32 + g * 8) ^ ((d & 7) << 3))]);
                o[nd] = __builtin_amdgcn_mfma_f32_16x16x32_bf16(pa, vf, o[nd], 0, 0, 0);
            }
        }
        __builtin_amdgcn_s_setprio(0);
        cur ^= 1;
    }
    #pragma unroll
    for (int r = 0; r < 4; ++r) {
        float ls = lrow[r];
        ls += __shfl_xor(ls, 1);
        ls += __shfl_xor(ls, 2);
        ls += __shfl_xor(ls, 4);
        ls += __shfl_xor(ls, 8);
        const float inv = 1.0f / ls;
        #pragma unroll
        for (int nd = 0; nd < 8; ++nd) o[nd][r] *= inv;
    }
    #pragma unroll
    for (int nd = 0; nd < 8; ++nd)
        #pragma unroll
        for (int r = 0; r < 4; ++r) {
            const int srow = q0 + g * 4 + r;
            attn[((size_t)b * SEQ + srow) * HDIM + h * HDHEAD + nd * 16 + c] = f2bf(o[nd][r]);
        }
}

// ---------------- output projection ----------------
// 128x128 tile, BK=64, 2-phase + hand-interleaved tile body (R12 pattern)
__global__ __launch_bounds__(256) void k_gemm_out(
    const unsigned short* __restrict__ attn, const unsigned short* __restrict__ WTo,
    const float* __restrict__ bo, float* __restrict__ out) {
    __shared__ __align__(16) unsigned char SMEM[65536];
    unsigned short* As0 = (unsigned short*)SMEM;           // [2][128*64]
    unsigned short* Bs0 = (unsigned short*)(SMEM + 32768);
    const int m0 = blockIdx.y * 128;
    const int n0 = blockIdx.x * 128;
    const int t = threadIdx.x;
    const int lane = t & 63, w = t >> 6;
    const int c = lane & 15, g = lane >> 4;

    const int lrow = lane >> 3;
    const int lslot = (lane & 7) ^ lrow;
    const unsigned short* aB = attn + (size_t)(m0 + lrow) * HDIM + lslot * 8;
    const unsigned short* bB = WTo + (size_t)(n0 + lrow) * HDIM + lslot * 8;

    f32x4 acc[2][8] = {};
    const int NT = HDIM / 64;  // 32

    #pragma unroll
    for (int j = 0; j < 4; ++j) {
        const int ch = w * 4 + j;
        gl16(aB + (size_t)(ch * 8) * HDIM, &As0[ch * 512]);
        gl16(bB + (size_t)(ch * 8) * HDIM, &Bs0[ch * 512]);
    }
#define MF(A_, B_, C_) __builtin_amdgcn_mfma_f32_16x16x32_bf16(A_, B_, C_, 0, 0, 0)
#define ORDA(D_, MI, KC) { const int ar_ = w * 32 + (MI) * 16 + c; const int sa_ = ar_ & 7; \
    D_ = as_bf(*(const us8*)&As0[cb * 8192 + ar_ * 64 + ((((KC) * 4 + g) ^ sa_) << 3)]); }
#define ORDB0(NI) { const int br_ = (NI) * 16 + c; const int sb_ = br_ & 7; \
    b0[NI] = as_bf(*(const us8*)&Bs0[cb * 8192 + br_ * 64 + ((g ^ sb_) << 3)]); }
#define ORDB1(NI) { const int br_ = (NI) * 16 + c; const int sb_ = br_ & 7; \
    b1[NI] = as_bf(*(const us8*)&Bs0[cb * 8192 + br_ * 64 + (((4 + g) ^ sb_) << 3)]); }
    for (int kt = 0; kt < NT; ++kt) {
        const int cb = kt & 1;
        if (kt + 1 < NT) {
            const int k1 = (kt + 1) * 64;
            #pragma unroll
            for (int j = 0; j < 4; ++j) {
                const int ch = w * 4 + j;
                gl16(aB + (size_t)(ch * 8) * HDIM + k1, &As0[(cb ^ 1) * 8192 + ch * 512]);
                gl16(bB + (size_t)(ch * 8) * HDIM + k1, &Bs0[(cb ^ 1) * 8192 + ch * 512]);
            }
            asm volatile("s_waitcnt vmcnt(8)" ::: "memory");
        } else {
            asm volatile("s_waitcnt vmcnt(0)" ::: "memory");
        }
        __builtin_amdgcn_s_barrier();
        bf16x8 b0[8], b1[8], a00, a01, a10, a11;
        ORDA(a00, 0, 0) ORDA(a01, 1, 0)
        ORDB0(0) ORDB0(1) ORDB0(2) ORDB0(3)
        __builtin_amdgcn_s_setprio(1);
        ORDB0(4) acc[0][0] = MF(a00, b0[0], acc[0][0]);
        ORDB0(5) acc[0][1] = MF(a00, b0[1], acc[0][1]);
        ORDB0(6) acc[0][2] = MF(a00, b0[2], acc[0][2]);
        ORDB0(7) acc[0][3] = MF(a00, b0[3], acc[0][3]);
        ORDB1(0) acc[0][4] = MF(a00, b0[4], acc[0][4]);
        ORDB1(1) acc[0][5] = MF(a00, b0[5], acc[0][5]);
        ORDB1(2) acc[0][6] = MF(a00, b0[6], acc[0][6]);
        ORDB1(3) acc[0][7] = MF(a00, b0[7], acc[0][7]);
        ORDB1(4) acc[1][0] = MF(a01, b0[0], acc[1][0]);
        ORDB1(5) acc[1][1] = MF(a01, b0[1], acc[1][1]);
        ORDB1(6) acc[1][2] = MF(a01, b0[2], acc[1][2]);
        ORDB1(7) acc[1][3] = MF(a01, b0[3], acc[1][3]);
        ORDA(a10, 0, 1)   acc[1][4] = MF(a01, b0[4], acc[1][4]);
        ORDA(a11, 1, 1)   acc[1][5] = MF(a01, b0[5], acc[1][5]);
        acc[1][6] = MF(a01, b0[6], acc[1][6]);
        acc[1][7] = MF(a01, b0[7], acc[1][7]);
        acc[0][0] = MF(a10, b1[0], acc[0][0]);
        acc[0][1] = MF(a10, b1[1], acc[0][1]);
        acc[0][2] = MF(a10, b1[2], acc[0][2]);
        acc[0][3] = MF(a10, b1[3], acc[0][3]);
        acc[0][4] = MF(a10, b1[4], acc[0][4]);
        acc[0][5] = MF(a10, b1[5], acc[0][5]);
        acc[0][6] = MF(a10, b1[6], acc[0][6]);
        acc[0][7] = MF(a10, b1[7], acc[0][7]);
        acc[1][0] = MF(a11, b1[0], acc[1][0]);
        acc[1][1] = MF(a11, b1[1], acc[1][1]);
        acc[1][2] = MF(a11, b1[2], acc[1][2]);
        acc[1][3] = MF(a11, b1[3], acc[1][3]);
        acc[1][4] = MF(a11, b1[4], acc[1][4]);
        acc[1][5] = MF(a11, b1[5], acc[1][5]);
        acc[1][6] = MF(a11, b1[6], acc[1][6]);
        acc[1][7] = MF(a11, b1[7], acc[1][7]);
        __builtin_amdgcn_s_setprio(0);
        __builtin_amdgcn_s_barrier();
    }
#undef MF
#undef ORDA
#undef ORDB0
#undef ORDB1

    // LDS-staged full-line epilogue: per-wave [16][132] fp32
    float* myF = (float*)SMEM + w * (16 * 132);
    const int qrow = lane & 31;
    for (int mi = 0; mi < 2; ++mi) {
        __syncthreads();
        #pragma unroll
        for (int r = 0; r < 4; ++r) {
            const int row = g * 4 + r;
            #pragma unroll
            for (int ni = 0; ni < 8; ++ni)
                myF[row * 132 + ni * 16 + c] = acc[mi][ni][r];
        }
        __syncthreads();
        #pragma unroll
        for (int j = 0; j < 8; ++j) {
            const int rrow = 2 * j + (lane >> 5);
            const int row = m0 + w * 32 + mi * 16 + rrow;
            f32x4 v4 = *(const f32x4*)&myF[rrow * 132 + qrow * 4];
            const f32x4 b4 = *(const f32x4*)&bo[n0 + qrow * 4];
            v4 += b4;
            *(f32x4*)&out[(size_t)row * HDIM + n0 + qrow * 4] = v4;
        }
    }
}

extern "C" void kernel_launch(void* const* d_in, const int* in_sizes, int n_in,
                              void* d_out, int out_size, void* d_ws, size_t ws_size,
                              hipStream_t stream) {
    const float* hidden = (const float*)d_in[0];
    // d_in[1] = mask (causality computed analytically)
    const float* past_key = (const float*)d_in[2];
    const float* past_value = (const float*)d_in[3];
    const float* Wq = (const float*)d_in[4];
    const float* bq = (const float*)d_in[5];
    const float* Wk = (const float*)d_in[6];
    const float* bk = (const float*)d_in[7];
    const float* Wv = (const float*)d_in[8];
    const float* bv = (const float*)d_in[9];
    const float* Wo = (const float*)d_in[10];
    const float* bo = (const float*)d_in[11];

    float* out0 = (float*)d_out;
    float* outK = out0 + (size_t)NB * SEQ * HDIM;
    float* outV = outK + (size_t)NB * NHEADS * STOT * HDHEAD;

    char* ws = (char*)d_ws;
    float2* csT = (float2*)(ws + OFF_CS);
    unsigned short* hsb = (unsigned short*)(ws + OFF_HSB);
    unsigned short* WT = (unsigned short*)(ws + OFF_WT);
    unsigned short* qbf = (unsigned short*)(ws + OFF_QBF);
    unsigned short* Kc2 = (unsigned short*)(ws + OFF_KC);
    unsigned short* Vt2 = (unsigned short*)(ws + OFF_VT);
    unsigned short* attnb = (unsigned short*)(ws + OFF_ATT);
    float* Cq = out0;                       // out0 region as scratch (written last)
    float* Ck = (float*)(ws + OFF_ATT);     // ATT region as scratch (attn writes later)

    k_prep<<<dim3(8192), dim3(256), 0, stream>>>(
        hidden, hsb, csT, Wq, Wk, Wv, Wo, WT);
    k_gemm_qkv<<<dim3(256), dim3(512), 0, stream>>>(
        hsb, WT, bv, Cq, Ck, outV, past_key, past_value, outK, Kc2, Vt2);
    k_post<<<dim3(16, 32), dim3(256), 0, stream>>>(
        Cq, Ck, outV, bq, bk, csT, qbf, Kc2, Vt2, outK);
    k_attn<<<dim3(512), dim3(256), 0, stream>>>(qbf, Kc2, Vt2, attnb);
    k_gemm_out<<<dim3(16, 16), dim3(256), 0, stream>>>(
        attnb, WT + (size_t)3 * HDIM * HDIM, bo, out0);
}

// Round 19
// 201.802 us; speedup vs baseline: 1.0132x; 1.0132x over previous
//
#include <hip/hip_runtime.h>
#include <hip/hip_bf16.h>
#include <math.h>

#define NB 2
#define SEQ 1024
#define HDIM 2048
#define NHEADS 16
#define HDHEAD 128
#define PASTN 1024
#define STOT 2048
#define MROWS 2048   // NB*SEQ

typedef __attribute__((ext_vector_type(4))) float f32x4;
typedef __attribute__((ext_vector_type(8))) __bf16 bf16x8;
typedef __attribute__((ext_vector_type(8))) unsigned short us8;
typedef __attribute__((ext_vector_type(4))) unsigned short us4;

__device__ __forceinline__ unsigned short f2bf(float f) {
    union { float f; unsigned int u; } v; v.f = f;
    unsigned int u = v.u;
    u += 0x7FFFu + ((u >> 16) & 1u);
    return (unsigned short)(u >> 16);
}
__device__ __forceinline__ bf16x8 as_bf(us8 u) { return __builtin_bit_cast(bf16x8, u); }

// async global->LDS, 16B per lane; LDS dest is wave-uniform base + lane*16
__device__ __forceinline__ void gl16(const unsigned short* g, unsigned short* l) {
    __builtin_amdgcn_global_load_lds(
        (const __attribute__((address_space(1))) void*)g,
        (__attribute__((address_space(3))) void*)l, 16, 0, 0);
}

// ---------------- ws layout (bytes) ----------------
#define OFF_CS  ((size_t)0)                              // float2[SEQ*64] = 512 KB
#define OFF_HSB (OFF_CS  + (size_t)SEQ*64*8)
#define OFF_WT  (OFF_HSB + (size_t)MROWS*HDIM*2)
#define OFF_QBF (OFF_WT  + (size_t)4*HDIM*HDIM*2)
#define OFF_KC  (OFF_QBF + (size_t)NB*NHEADS*SEQ*HDHEAD*2)
#define OFF_VT  (OFF_KC  + (size_t)NB*NHEADS*STOT*HDHEAD*2)
#define OFF_ATT (OFF_VT  + (size_t)NB*NHEADS*HDHEAD*STOT*2)
// NOTE: the ATT region (16.8 MB) doubles as C_k scratch (2048x2048 fp32) for
// k_gemm_qkv -> k_post; attn overwrites it afterwards (stream-ordered, safe).
// C_q scratch (2048x2048 fp32) lives in d_out's out0 region (written last).

// K cache tiled layout: Kc2[(bh*32+kt)*8192 + pr*128 + (d ^ ((p&7)<<3))], pr=p&63
// V cache tiled layout: Vt2[(bh*32+kt)*8192 + d*64 + ((p&63) ^ ((d&7)<<3))]

// ---------------- prep: hidden cvt + rope table | W transpose ----------------
__global__ void k_prep(const float* __restrict__ in, unsigned short* __restrict__ hsb,
                       float2* __restrict__ csT,
                       const float* __restrict__ Wq, const float* __restrict__ Wk,
                       const float* __restrict__ Wv, const float* __restrict__ Wo,
                       unsigned short* __restrict__ WT) {
    __shared__ unsigned short tsh[64][65];
    const int bid = blockIdx.x, tid = threadIdx.x;
    if (bid < 4096) {
        const int i = (bid * 256 + tid) * 4;           // over 4M elems
        f32x4 v = *(const f32x4*)(in + i);
        us4 o;
        o.x = f2bf(v.x); o.y = f2bf(v.y); o.z = f2bf(v.z); o.w = f2bf(v.w);
        *(us4*)(hsb + i) = o;
        if (bid < 256) {                                // rope cos/sin table
            const int idx = bid * 256 + tid;
            const int s = idx >> 6, fi = idx & 63;
            float inv = 1.0f / powf(10000.0f, (float)fi / 64.0f);
            float a = (float)s * inv;
            csT[idx] = make_float2(cosf(a), sinf(a));
        }
    } else {
        // W [K][N] fp32 -> WT [N][K] bf16 ; 64x64 tile, full-line writes
        const int idx = bid - 4096;
        const int z = idx >> 10;
        const int rem = idx & 1023;
        const int n0 = (rem & 31) * 64, k0 = (rem >> 5) * 64;
        const float* W = (z == 0) ? Wq : (z == 1) ? Wk : (z == 2) ? Wv : Wo;
        unsigned short* out = WT + (size_t)z * HDIM * HDIM;
        const int tx = tid & 63, ty = tid >> 6;         // (64,4)
        #pragma unroll
        for (int j = 0; j < 16; ++j) {
            const int kk = ty + j * 4;
            tsh[tx][kk] = f2bf(W[(size_t)(k0 + kk) * HDIM + n0 + tx]);   // tsh[n][k]
        }
        __syncthreads();
        #pragma unroll
        for (int j = 0; j < 16; ++j) {
            const int nn = ty + j * 4;
            out[(size_t)(n0 + nn) * HDIM + k0 + tx] = tsh[nn][tx];       // 128B row runs
        }
    }
}

// ---------------- QKV GEMM (blocks 0-191) + pastk (192-223) + pastv (224-255) ----
__global__ __launch_bounds__(512, 2) void k_gemm_qkv(
    const unsigned short* __restrict__ hsb, const unsigned short* __restrict__ WT,
    const float* __restrict__ bv,
    float* __restrict__ Cq, float* __restrict__ Ck, float* __restrict__ outV,
    const float* __restrict__ pk, const float* __restrict__ pv,
    float* __restrict__ outK, unsigned short* __restrict__ Kc2,
    unsigned short* __restrict__ Vt2) {
    __shared__ __align__(16) unsigned short As[2][256 * 64];
    __shared__ __align__(16) unsigned short Bs[2][256 * 64];

    const int bid = blockIdx.x;
    const int t = threadIdx.x;

    if (bid >= 192) {
        if (bid < 224) {
            // ---- pastk: fp32 copy + bf16 tiled/swizzled (grid-stride, 512 thr) ----
            const int blk = bid - 192;   // 0..31
            for (int it = 0; it < 64; ++it) {
                const size_t e = ((size_t)(blk * 64 + it) * 512 + t) * 4;
                const size_t bh = e >> 17;
                const int p = (int)((e >> 7) & 1023);
                const int d0 = (int)(e & 127);
                f32x4 v = *(const f32x4*)(pk + e);
                *(f32x4*)(outK + e + (bh << 17)) = v;
                us4 u;
                u.x = f2bf(v.x); u.y = f2bf(v.y); u.z = f2bf(v.z); u.w = f2bf(v.w);
                *(us4*)(Kc2 + ((bh * 32 + (p >> 6)) << 13) + (size_t)(p & 63) * 128 +
                        (d0 ^ ((p & 7) << 3))) = u;
            }
        } else {
            // ---- pastv: fp32 copy + tiled/swizzled bf16 (32 tiles/block, 512 thr) ----
            const int blk = bid - 224;   // 0..31
            unsigned short (*tsh)[65] = (unsigned short (*)[65])As;   // reuse LDS
            const int tx = t & 63, ty = t >> 6;     // (64,8)
            for (int tt = 0; tt < 32; ++tt) {
                const int tile = blk * 32 + tt;
                const int bh = tile >> 5;
                const int rem = tile & 31;
                const int p0 = (rem & 15) * 64, d0 = (rem >> 4) * 64;
                const float* src = pv + ((size_t)bh * PASTN + p0) * HDHEAD + d0;
                float* dst = outV + ((size_t)bh * STOT + p0) * HDHEAD + d0;
                #pragma unroll
                for (int j = 0; j < 8; ++j) {
                    const int pp = ty + j * 8;
                    float v = src[(size_t)pp * HDHEAD + tx];
                    dst[(size_t)pp * HDHEAD + tx] = v;
                    tsh[tx][pp] = f2bf(v);           // tsh[d_off][p_off]
                }
                __syncthreads();
                unsigned short* vt = Vt2 + (((size_t)bh * 32 + (p0 >> 6)) << 13);
                #pragma unroll
                for (int j = 0; j < 8; ++j) {
                    const int dd = ty + j * 8;
                    const int d = d0 + dd;
                    vt[(size_t)d * 64 + (tx ^ ((d & 7) << 3))] = tsh[dd][tx];
                }
                __syncthreads();
            }
        }
        return;
    }

    const int swz = (bid & 7) * 24 + (bid >> 3);
    const int mb = swz & 7;
    const int nbz = swz >> 3;
    const int z = nbz >> 3;            // 0:q 1:k 2:v
    const int nb8 = nbz & 7;
    const int m0 = mb * 256;
    const int n0 = nb8 * 256;
    const unsigned short* Wz = WT + (size_t)z * HDIM * HDIM;

    const int lane = t & 63, wid = t >> 6;
    const int wr = wid >> 1, wc = wid & 1;
    const int c = lane & 15, g = lane >> 4;

    const int lrow8 = lane >> 3;
    const int lslot = (lane & 7) ^ lrow8;
    const unsigned short* aB = hsb + (size_t)(m0 + lrow8) * HDIM + lslot * 8;
    const unsigned short* bB = Wz + (size_t)(n0 + lrow8) * HDIM + lslot * 8;

    auto stage = [&](int kt, int pb) {
        const int k0s = kt * 64;
        #pragma unroll
        for (int j = 0; j < 4; ++j) {
            const int ch = wid * 4 + j;
            gl16(aB + (size_t)(ch * 8) * HDIM + k0s, &As[pb][ch * 512]);
            gl16(bB + (size_t)(ch * 8) * HDIM + k0s, &Bs[pb][ch * 512]);
        }
    };

    f32x4 acc[4][8] = {};
    const int NT = HDIM / 64;  // 32

    stage(0, 0);
    stage(1, 1);

#define MF(A_, B_, C_) __builtin_amdgcn_mfma_f32_16x16x32_bf16(A_, B_, C_, 0, 0, 0)
#define RDA(D0, D1, MI) { const int ar_ = wr * 64 + (MI) * 16 + c; const int sa_ = ar_ & 7; \
    D0 = as_bf(*(const us8*)&As[p][ar_ * 64 + ((g ^ sa_) << 3)]); \
    D1 = as_bf(*(const us8*)&As[p][ar_ * 64 + (((4 + g) ^ sa_) << 3)]); }
#define RDB0(NI) { const int br_ = wc * 128 + (NI) * 16 + c; const int sb_ = br_ & 7; \
    b0[NI] = as_bf(*(const us8*)&Bs[p][br_ * 64 + ((g ^ sb_) << 3)]); }
#define RDB1(NI) { const int br_ = wc * 128 + (NI) * 16 + c; const int sb_ = br_ & 7; \
    b1[NI] = as_bf(*(const us8*)&Bs[p][br_ * 64 + (((4 + g) ^ sb_) << 3)]); }

    for (int kt = 0; kt < NT; ++kt) {
        const int p = kt & 1;
        if (kt + 1 < NT) {
            asm volatile("s_waitcnt vmcnt(8)" ::: "memory");
        } else {
            asm volatile("s_waitcnt vmcnt(0)" ::: "memory");
        }
        __builtin_amdgcn_s_barrier();

        bf16x8 b0[8], b1[8];
        bf16x8 a0c, a1c, a0n, a1n;
        RDA(a0c, a1c, 0)
        RDB0(0) RDB0(1) RDB0(2) RDB0(3)
        __builtin_amdgcn_s_setprio(1);
        // ---- mi=0: interleave remaining B reads 1-per-MFMA ----
        RDB0(4) acc[0][0] = MF(a0c, b0[0], acc[0][0]);
        RDB0(5) acc[0][1] = MF(a0c, b0[1], acc[0][1]);
        RDB0(6) acc[0][2] = MF(a0c, b0[2], acc[0][2]);
        RDB0(7) acc[0][3] = MF(a0c, b0[3], acc[0][3]);
        RDB1(0) acc[0][4] = MF(a0c, b0[4], acc[0][4]);
        RDB1(1) acc[0][5] = MF(a0c, b0[5], acc[0][5]);
        RDB1(2) acc[0][6] = MF(a0c, b0[6], acc[0][6]);
        RDB1(3) acc[0][7] = MF(a0c, b0[7], acc[0][7]);
        RDB1(4) acc[0][0] = MF(a1c, b1[0], acc[0][0]);
        RDB1(5) acc[0][1] = MF(a1c, b1[1], acc[0][1]);
        RDB1(6) acc[0][2] = MF(a1c, b1[2], acc[0][2]);
        RDB1(7) acc[0][3] = MF(a1c, b1[3], acc[0][3]);
        RDA(a0n, a1n, 1)
        acc[0][4] = MF(a1c, b1[4], acc[0][4]);
        acc[0][5] = MF(a1c, b1[5], acc[0][5]);
        acc[0][6] = MF(a1c, b1[6], acc[0][6]);
        acc[0][7] = MF(a1c, b1[7], acc[0][7]);
        // ---- mi=1 (uses a0n/a1n), prefetch A(2) mid-cluster ----
        acc[1][0] = MF(a0n, b0[0], acc[1][0]);
        acc[1][1] = MF(a0n, b0[1], acc[1][1]);
        acc[1][2] = MF(a0n, b0[2], acc[1][2]);
        acc[1][3] = MF(a0n, b0[3], acc[1][3]);
        acc[1][4] = MF(a0n, b0[4], acc[1][4]);
        acc[1][5] = MF(a0n, b0[5], acc[1][5]);
        acc[1][6] = MF(a0n, b0[6], acc[1][6]);
        acc[1][7] = MF(a0n, b0[7], acc[1][7]);
        RDA(a0c, a1c, 2)
        acc[1][0] = MF(a1n, b1[0], acc[1][0]);
        acc[1][1] = MF(a1n, b1[1], acc[1][1]);
        acc[1][2] = MF(a1n, b1[2], acc[1][2]);
        acc[1][3] = MF(a1n, b1[3], acc[1][3]);
        acc[1][4] = MF(a1n, b1[4], acc[1][4]);
        acc[1][5] = MF(a1n, b1[5], acc[1][5]);
        acc[1][6] = MF(a1n, b1[6], acc[1][6]);
        acc[1][7] = MF(a1n, b1[7], acc[1][7]);
        // ---- mi=2 (uses a0c/a1c), prefetch A(3) mid-cluster ----
        acc[2][0] = MF(a0c, b0[0], acc[2][0]);
        acc[2][1] = MF(a0c, b0[1], acc[2][1]);
        acc[2][2] = MF(a0c, b0[2], acc[2][2]);
        acc[2][3] = MF(a0c, b0[3], acc[2][3]);
        acc[2][4] = MF(a0c, b0[4], acc[2][4]);
        acc[2][5] = MF(a0c, b0[5], acc[2][5]);
        acc[2][6] = MF(a0c, b0[6], acc[2][6]);
        acc[2][7] = MF(a0c, b0[7], acc[2][7]);
        RDA(a0n, a1n, 3)
        acc[2][0] = MF(a1c, b1[0], acc[2][0]);
        acc[2][1] = MF(a1c, b1[1], acc[2][1]);
        acc[2][2] = MF(a1c, b1[2], acc[2][2]);
        acc[2][3] = MF(a1c, b1[3], acc[2][3]);
        acc[2][4] = MF(a1c, b1[4], acc[2][4]);
        acc[2][5] = MF(a1c, b1[5], acc[2][5]);
        acc[2][6] = MF(a1c, b1[6], acc[2][6]);
        acc[2][7] = MF(a1c, b1[7], acc[2][7]);
        // ---- mi=3 (uses a0n/a1n) ----
        acc[3][0] = MF(a0n, b0[0], acc[3][0]);
        acc[3][1] = MF(a0n, b0[1], acc[3][1]);
        acc[3][2] = MF(a0n, b0[2], acc[3][2]);
        acc[3][3] = MF(a0n, b0[3], acc[3][3]);
        acc[3][4] = MF(a0n, b0[4], acc[3][4]);
        acc[3][5] = MF(a0n, b0[5], acc[3][5]);
        acc[3][6] = MF(a0n, b0[6], acc[3][6]);
        acc[3][7] = MF(a0n, b0[7], acc[3][7]);
        acc[3][0] = MF(a1n, b1[0], acc[3][0]);
        acc[3][1] = MF(a1n, b1[1], acc[3][1]);
        acc[3][2] = MF(a1n, b1[2], acc[3][2]);
        acc[3][3] = MF(a1n, b1[3], acc[3][3]);
        acc[3][4] = MF(a1n, b1[4], acc[3][4]);
        acc[3][5] = MF(a1n, b1[5], acc[3][5]);
        acc[3][6] = MF(a1n, b1[6], acc[3][6]);
        acc[3][7] = MF(a1n, b1[7], acc[3][7]);
        __builtin_amdgcn_s_setprio(0);
        __builtin_amdgcn_s_barrier();       // all reads of buf p done
        if (kt + 2 < NT) stage(kt + 2, p);
    }
#undef MF
#undef RDA
#undef RDB0
#undef RDB1

    // ---- minimal epilogue ----
    if (z < 2) {
        float* Cz = (z == 0) ? Cq : Ck;
        #pragma unroll
        for (int mi = 0; mi < 4; ++mi) {
            #pragma unroll
            for (int r = 0; r < 4; ++r) {
                const size_t row = (size_t)(m0 + wr * 64 + mi * 16 + g * 4 + r);
                #pragma unroll
                for (int ni = 0; ni < 8; ++ni)
                    Cz[row * HDIM + n0 + wc * 128 + ni * 16 + c] = acc[mi][ni][r];
            }
        }
    } else {
        const int h = nb8 * 2 + wc;
        const int b = m0 >> 10;
        const size_t bh2 = (size_t)(b * NHEADS + h);
        float bias8[8];
        #pragma unroll
        for (int ni = 0; ni < 8; ++ni) bias8[ni] = bv[n0 + wc * 128 + ni * 16 + c];
        #pragma unroll
        for (int mi = 0; mi < 4; ++mi) {
            #pragma unroll
            for (int r = 0; r < 4; ++r) {
                const int row = m0 + wr * 64 + mi * 16 + g * 4 + r;
                const int s = row & 1023;
                const int p = PASTN + s;
                #pragma unroll
                for (int ni = 0; ni < 8; ++ni)
                    outV[(bh2 * STOT + p) * HDHEAD + ni * 16 + c] = acc[mi][ni][r] + bias8[ni];
            }
        }
    }
}

// ---------------- post: bias + RoPE + cache-pack (memory-bound) ----------------
__global__ __launch_bounds__(256) void k_post(
    const float* __restrict__ Cq, const float* __restrict__ Ck,
    const float* __restrict__ outV,
    const float* __restrict__ bq, const float* __restrict__ bk,
    const float2* __restrict__ csT,
    unsigned short* __restrict__ qbf, unsigned short* __restrict__ Kc2,
    unsigned short* __restrict__ Vt2, float* __restrict__ outK) {
    __shared__ unsigned short tv[128][80];
    const int stile = blockIdx.x;       // 0..15
    const int bh = blockIdx.y;          // 0..31
    const int b = bh >> 4, h = bh & 15;
    const int tid = threadIdx.x;
    const int dq = (tid & 15) * 4;      // d0 in [0,64)
    const int sl0 = tid >> 4;           // 0..15
    const int s0 = stile * 64;
    const int ktv = 16 + stile;
    const float qscale = 0.08838834764831845f * 1.44269504088896f;  // 1/sqrt(128)*log2e
    unsigned short* kc = Kc2 + (((size_t)bh * 32 + ktv) << 13);
    unsigned short* vt = Vt2 + (((size_t)bh * 32 + ktv) << 13);

    float bql[4], bqh[4], bkl[4], bkh[4];
    #pragma unroll
    for (int i = 0; i < 4; ++i) {
        bql[i] = bq[h * 128 + dq + i];      bqh[i] = bq[h * 128 + 64 + dq + i];
        bkl[i] = bk[h * 128 + dq + i];      bkh[i] = bk[h * 128 + 64 + dq + i];
    }

    #pragma unroll
    for (int ps = 0; ps < 4; ++ps) {
        const int sl = sl0 + ps * 16;
        const int s = s0 + sl;
        const size_t row = (size_t)b * 1024 + s;
        const int p = PASTN + s;
        float2 cs4[4];
        #pragma unroll
        for (int i = 0; i < 4; ++i) cs4[i] = csT[s * 64 + dq + i];
        const int swzp = (sl & 7) << 3;     // p&7 == sl&7 (s0 is 64-aligned)
        // ---- Q ----
        {
            const f32x4 a = *(const f32x4*)&Cq[row * HDIM + h * 128 + dq];
            const f32x4 bb = *(const f32x4*)&Cq[row * HDIM + h * 128 + dq + 64];
            us4 lo, hi;
            #pragma unroll
            for (int i = 0; i < 4; ++i) {
                const float va = a[i] + bql[i];
                const float vb = bb[i] + bqh[i];
                lo[i] = f2bf((va * cs4[i].x - vb * cs4[i].y) * qscale);
                hi[i] = f2bf((vb * cs4[i].x + va * cs4[i].y) * qscale);
            }
            unsigned short* qrow = qbf + ((size_t)bh * SEQ + s) * HDHEAD;
            *(us4*)&qrow[dq] = lo;
            *(us4*)&qrow[dq + 64] = hi;
        }
        // ---- K ----
        {
            const f32x4 a = *(const f32x4*)&Ck[row * HDIM + h * 128 + dq];
            const f32x4 bb = *(const f32x4*)&Ck[row * HDIM + h * 128 + dq + 64];
            f32x4 rl, rh;
            us4 lo, hi;
            #pragma unroll
            for (int i = 0; i < 4; ++i) {
                const float va = a[i] + bkl[i];
                const float vb = bb[i] + bkh[i];
                rl[i] = va * cs4[i].x - vb * cs4[i].y;
                rh[i] = vb * cs4[i].x + va * cs4[i].y;
                lo[i] = f2bf(rl[i]);
                hi[i] = f2bf(rh[i]);
            }
            float* krow = outK + ((size_t)bh * STOT + p) * HDHEAD;
            *(f32x4*)&krow[dq] = rl;
            *(f32x4*)&krow[dq + 64] = rh;
            *(us4*)&kc[(size_t)sl * 128 + (dq ^ swzp)] = lo;
            *(us4*)&kc[(size_t)sl * 128 + ((dq + 64) ^ swzp)] = hi;
        }
        // ---- V: stage to LDS for transpose ----
        {
            const f32x4 va = *(const f32x4*)&outV[((size_t)bh * STOT + p) * HDHEAD + dq];
            const f32x4 vb = *(const f32x4*)&outV[((size_t)bh * STOT + p) * HDHEAD + dq + 64];
            #pragma unroll
            for (int i = 0; i < 4; ++i) {
                tv[dq + i][sl] = f2bf(va[i]);
                tv[dq + 64 + i][sl] = f2bf(vb[i]);
            }
        }
    }
    __syncthreads();
    // ---- Vt2 write: full-row us4 runs ----
    const int d = tid >> 1;
    const int ph = (tid & 1) * 32;
    const int swzd = (d & 7) << 3;
    #pragma unroll
    for (int i = 0; i < 8; ++i) {
        const int pp = ph + i * 4;
        us4 u;
        u.x = tv[d][pp]; u.y = tv[d][pp + 1]; u.z = tv[d][pp + 2]; u.w = tv[d][pp + 3];
        *(us4*)&vt[(size_t)d * 64 + (pp ^ swzd)] = u;
    }
}

// ---------------- flash attention: 4 waves, q-tile 64, 512 blocks ----------------
// XCD-affine (bh = bid&31) + causal load balance: bid<256 -> qt=bid>>5 (0..7),
// bid>=256 -> qt=15-((bid>>5)&7) (15..8). Paired blocks (bid, bid+256) share a CU;
// per-CU tile total = (17+qt)+(32-qt) = 49, exactly balanced.
__global__ __launch_bounds__(256) void k_attn(
    const unsigned short* __restrict__ qbf, const unsigned short* __restrict__ Kc2,
    const unsigned short* __restrict__ Vt2, unsigned short* __restrict__ attn) {
    __shared__ __align__(16) unsigned short Ks[2][64 * 128];  // 32 KB
    __shared__ __align__(16) unsigned short Vs[128 * 64];     // 16 KB
    __shared__ __align__(16) unsigned short P[4][16][72];     // 9 KB
    const int bid = blockIdx.x;
    const int bh = bid & 31;
    const int qt = (bid < 256) ? (bid >> 5) : (15 - ((bid >> 5) & 7));
    const int b = bh >> 4, h = bh & 15;
    const int t = threadIdx.x, lane = t & 63, w = t >> 6;     // 4 waves
    const int c = lane & 15, g = lane >> 4;
    const int q0 = qt * 64 + w * 16;
    const unsigned short* Qb = qbf + ((size_t)bh * SEQ + q0) * HDHEAD;
    const unsigned short* Kbase = Kc2 + ((size_t)bh << 18);
    const unsigned short* Vbase = Vt2 + ((size_t)bh << 18);

    bf16x8 qf[4];
    #pragma unroll
    for (int kf = 0; kf < 4; ++kf)
        qf[kf] = as_bf(*(const us8*)(Qb + (size_t)c * HDHEAD + kf * 32 + g * 8));

    // prologue: stage K tile 0 (16 chunks over 4 waves)
    #pragma unroll
    for (int j = 0; j < 4; ++j) {
        const int ch = w * 4 + j;
        gl16(Kbase + ch * 512 + lane * 8, &Ks[0][ch * 512]);
    }

    f32x4 o[8] = {};
    float mrow[4] = {-1e30f, -1e30f, -1e30f, -1e30f};
    float lrow[4] = {0.f, 0.f, 0.f, 0.f};
    const int nkt = 17 + qt;
    int cur = 0;
    for (int kt = 0; kt < nkt; ++kt) {
        asm volatile("s_waitcnt vmcnt(0)" ::: "memory");
        __builtin_amdgcn_s_barrier();
        const unsigned short* Vg = Vbase + ((size_t)kt << 13);
        #pragma unroll
        for (int j = 0; j < 4; ++j) {
            const int ch = w * 4 + j;
            gl16(Vg + ch * 512 + lane * 8, &Vs[ch * 512]);
        }
        if (kt + 1 < nkt) {
            const unsigned short* Kg = Kbase + ((size_t)(kt + 1) << 13);
            #pragma unroll
            for (int j = 0; j < 4; ++j) {
                const int ch = w * 4 + j;
                gl16(Kg + ch * 512 + lane * 8, &Ks[cur ^ 1][ch * 512]);
            }
        }
        // QK^T from Ks[cur]
        f32x4 sa[4] = {};
        #pragma unroll
        for (int nf = 0; nf < 4; ++nf) {
            const int row = nf * 16 + c;
            const int swzr = (row & 7) << 3;
            #pragma unroll
            for (int kf = 0; kf < 4; ++kf) {
                bf16x8 kf8 = as_bf(*(const us8*)&Ks[cur][row * 128 + ((kf * 32 + g * 8) ^ swzr)]);
                sa[nf] = __builtin_amdgcn_mfma_f32_16x16x32_bf16(qf[kf], kf8, sa[nf], 0, 0, 0);
            }
        }
        const int k0 = kt * 64;
        if (k0 + 63 > PASTN + q0) {
            #pragma unroll
            for (int nf = 0; nf < 4; ++nf) {
                const int j = k0 + nf * 16 + c;
                #pragma unroll
                for (int r = 0; r < 4; ++r)
                    if (j > PASTN + q0 + g * 4 + r) sa[nf][r] = -1e30f;
            }
        }
        // defer-max online softmax (log2 domain)
        float pmax[4];
        #pragma unroll
        for (int r = 0; r < 4; ++r)
            pmax[r] = fmaxf(fmaxf(sa[0][r], sa[1][r]), fmaxf(sa[2][r], sa[3][r]));
        bool need = false;
        #pragma unroll
        for (int r = 0; r < 4; ++r) need = need || (pmax[r] > mrow[r] + 12.0f);
        if (__any(need)) {
            #pragma unroll
            for (int r = 0; r < 4; ++r) {
                float mx = pmax[r];
                mx = fmaxf(mx, __shfl_xor(mx, 1));
                mx = fmaxf(mx, __shfl_xor(mx, 2));
                mx = fmaxf(mx, __shfl_xor(mx, 4));
                mx = fmaxf(mx, __shfl_xor(mx, 8));
                const float mnew = fmaxf(mrow[r], mx);
                const float alpha = exp2f(mrow[r] - mnew);
                mrow[r] = mnew;
                lrow[r] *= alpha;
                #pragma unroll
                for (int nd = 0; nd < 8; ++nd) o[nd][r] *= alpha;
            }
        }
        #pragma unroll
        for (int r = 0; r < 4; ++r) {
            const float p0 = exp2f(sa[0][r] - mrow[r]);
            const float p1 = exp2f(sa[1][r] - mrow[r]);
            const float p2 = exp2f(sa[2][r] - mrow[r]);
            const float p3 = exp2f(sa[3][r] - mrow[r]);
            lrow[r] += (p0 + p1) + (p2 + p3);
            P[w][g * 4 + r][0 * 16 + c] = f2bf(p0);
            P[w][g * 4 + r][1 * 16 + c] = f2bf(p1);
            P[w][g * 4 + r][2 * 16 + c] = f2bf(p2);
            P[w][g * 4 + r][3 * 16 + c] = f2bf(p3);
        }
        if (kt + 1 < nkt) {
            asm volatile("s_waitcnt vmcnt(4)" ::: "memory");
        } else {
            asm volatile("s_waitcnt vmcnt(0)" ::: "memory");
        }
        __builtin_amdgcn_s_barrier();
        #pragma unroll
        for (int kf2 = 0; kf2 < 2; ++kf2) {
            const bf16x8 pa = as_bf(*(const us8*)&P[w][c][kf2 * 32 + g * 8]);
            #pragma unroll
            for (int nd = 0; nd < 8; ++nd) {
                const int d = nd * 16 + c;
                const bf16x8 vf = as_bf(*(const us8*)&Vs[d * 64 + ((kf2 * 32 + g * 8) ^ ((d & 7) << 3))]);
                o[nd] = __builtin_amdgcn_mfma_f32_16x16x32_bf16(pa, vf, o[nd], 0, 0, 0);
            }
        }
        cur ^= 1;
    }
    #pragma unroll
    for (int r = 0; r < 4; ++r) {
        float ls = lrow[r];
        ls += __shfl_xor(ls, 1);
        ls += __shfl_xor(ls, 2);
        ls += __shfl_xor(ls, 4);
        ls += __shfl_xor(ls, 8);
        const float inv = 1.0f / ls;
        #pragma unroll
        for (int nd = 0; nd < 8; ++nd) o[nd][r] *= inv;
    }
    #pragma unroll
    for (int nd = 0; nd < 8; ++nd)
        #pragma unroll
        for (int r = 0; r < 4; ++r) {
            const int srow = q0 + g * 4 + r;
            attn[((size_t)b * SEQ + srow) * HDIM + h * HDHEAD + nd * 16 + c] = f2bf(o[nd][r]);
        }
}

// ---------------- output projection ----------------
// 128x128 tile, BK=64, 2-phase pipeline + LDS-staged full-line epilogue (plain stores)
__global__ __launch_bounds__(256) void k_gemm_out(
    const unsigned short* __restrict__ attn, const unsigned short* __restrict__ WTo,
    const float* __restrict__ bo, float* __restrict__ out) {
    __shared__ __align__(16) unsigned char SMEM[65536];
    unsigned short* As0 = (unsigned short*)SMEM;           // [2][128*64]
    unsigned short* Bs0 = (unsigned short*)(SMEM + 32768);
    const int m0 = blockIdx.y * 128;
    const int n0 = blockIdx.x * 128;
    const int t = threadIdx.x;
    const int lane = t & 63, w = t >> 6;
    const int c = lane & 15, g = lane >> 4;

    const int lrow = lane >> 3;
    const int lslot = (lane & 7) ^ lrow;
    const unsigned short* aB = attn + (size_t)(m0 + lrow) * HDIM + lslot * 8;
    const unsigned short* bB = WTo + (size_t)(n0 + lrow) * HDIM + lslot * 8;

    f32x4 acc[2][8] = {};
    const int NT = HDIM / 64;  // 32

    #pragma unroll
    for (int j = 0; j < 4; ++j) {
        const int ch = w * 4 + j;
        gl16(aB + (size_t)(ch * 8) * HDIM, &As0[ch * 512]);
        gl16(bB + (size_t)(ch * 8) * HDIM, &Bs0[ch * 512]);
    }
    for (int kt = 0; kt < NT; ++kt) {
        const int cb = kt & 1;
        if (kt + 1 < NT) {
            const int k1 = (kt + 1) * 64;
            #pragma unroll
            for (int j = 0; j < 4; ++j) {
                const int ch = w * 4 + j;
                gl16(aB + (size_t)(ch * 8) * HDIM + k1, &As0[(cb ^ 1) * 8192 + ch * 512]);
                gl16(bB + (size_t)(ch * 8) * HDIM + k1, &Bs0[(cb ^ 1) * 8192 + ch * 512]);
            }
            asm volatile("s_waitcnt vmcnt(8)" ::: "memory");
        } else {
            asm volatile("s_waitcnt vmcnt(0)" ::: "memory");
        }
        __builtin_amdgcn_s_barrier();
        #pragma unroll
        for (int kc = 0; kc < 2; ++kc) {
            bf16x8 af[2];
            #pragma unroll
            for (int mi = 0; mi < 2; ++mi) {
                const int ar = w * 32 + mi * 16 + c;
                af[mi] = as_bf(*(const us8*)&As0[cb * 8192 + ar * 64 + (((kc * 4 + g) ^ (ar & 7)) << 3)]);
            }
            #pragma unroll
            for (int ni = 0; ni < 8; ++ni) {
                const int br = ni * 16 + c;
                bf16x8 bfrag = as_bf(*(const us8*)&Bs0[cb * 8192 + br * 64 + (((kc * 4 + g) ^ (br & 7)) << 3)]);
                acc[0][ni] = __builtin_amdgcn_mfma_f32_16x16x32_bf16(af[0], bfrag, acc[0][ni], 0, 0, 0);
                acc[1][ni] = __builtin_amdgcn_mfma_f32_16x16x32_bf16(af[1], bfrag, acc[1][ni], 0, 0, 0);
            }
        }
        __builtin_amdgcn_s_barrier();
    }

    // LDS-staged full-line epilogue: per-wave [16][132] fp32
    float* myF = (float*)SMEM + w * (16 * 132);
    const int qrow = lane & 31;
    for (int mi = 0; mi < 2; ++mi) {
        __syncthreads();
        #pragma unroll
        for (int r = 0; r < 4; ++r) {
            const int row = g * 4 + r;
            #pragma unroll
            for (int ni = 0; ni < 8; ++ni)
                myF[row * 132 + ni * 16 + c] = acc[mi][ni][r];
        }
        __syncthreads();
        #pragma unroll
        for (int j = 0; j < 8; ++j) {
            const int rrow = 2 * j + (lane >> 5);
            const int row = m0 + w * 32 + mi * 16 + rrow;
            f32x4 v4 = *(const f32x4*)&myF[rrow * 132 + qrow * 4];
            const f32x4 b4 = *(const f32x4*)&bo[n0 + qrow * 4];
            v4 += b4;
            *(f32x4*)&out[(size_t)row * HDIM + n0 + qrow * 4] = v4;
        }
    }
}

extern "C" void kernel_launch(void* const* d_in, const int* in_sizes, int n_in,
                              void* d_out, int out_size, void* d_ws, size_t ws_size,
                              hipStream_t stream) {
    const float* hidden = (const float*)d_in[0];
    // d_in[1] = mask (causality computed analytically)
    const float* past_key = (const float*)d_in[2];
    const float* past_value = (const float*)d_in[3];
    const float* Wq = (const float*)d_in[4];
    const float* bq = (const float*)d_in[5];
    const float* Wk = (const float*)d_in[6];
    const float* bk = (const float*)d_in[7];
    const float* Wv = (const float*)d_in[8];
    const float* bv = (const float*)d_in[9];
    const float* Wo = (const float*)d_in[10];
    const float* bo = (const float*)d_in[11];

    float* out0 = (float*)d_out;
    float* outK = out0 + (size_t)NB * SEQ * HDIM;
    float* outV = outK + (size_t)NB * NHEADS * STOT * HDHEAD;

    char* ws = (char*)d_ws;
    float2* csT = (float2*)(ws + OFF_CS);
    unsigned short* hsb = (unsigned short*)(ws + OFF_HSB);
    unsigned short* WT = (unsigned short*)(ws + OFF_WT);
    unsigned short* qbf = (unsigned short*)(ws + OFF_QBF);
    unsigned short* Kc2 = (unsigned short*)(ws + OFF_KC);
    unsigned short* Vt2 = (unsigned short*)(ws + OFF_VT);
    unsigned short* attnb = (unsigned short*)(ws + OFF_ATT);
    float* Cq = out0;                       // out0 region as scratch (written last)
    float* Ck = (float*)(ws + OFF_ATT);     // ATT region as scratch (attn writes later)

    k_prep<<<dim3(8192), dim3(256), 0, stream>>>(
        hidden, hsb, csT, Wq, Wk, Wv, Wo, WT);
    k_gemm_qkv<<<dim3(256), dim3(512), 0, stream>>>(
        hsb, WT, bv, Cq, Ck, outV, past_key, past_value, outK, Kc2, Vt2);
    k_post<<<dim3(16, 32), dim3(256), 0, stream>>>(
        Cq, Ck, outV, bq, bk, csT, qbf, Kc2, Vt2, outK);
    k_attn<<<dim3(512), dim3(256), 0, stream>>>(qbf, Kc2, Vt2, attnb);
    k_gemm_out<<<dim3(16, 16), dim3(256), 0, stream>>>(
        attnb, WT + (size_t)3 * HDIM * HDIM, bo, out0);
}